// Round 1
// baseline (432.940 us; speedup 1.0000x reference)
//
#include <hip/hip_runtime.h>

typedef float f32x4 __attribute__((ext_vector_type(4)));
typedef float f32x16 __attribute__((ext_vector_type(16)));
typedef __bf16 bf16x8 __attribute__((ext_vector_type(8)));

__device__ __forceinline__ unsigned f2mono(float f) {
  unsigned u = __float_as_uint(f);
  return (u & 0x80000000u) ? ~u : (u | 0x80000000u);
}
__device__ __forceinline__ float mono2f(unsigned u) {
  return (u & 0x80000000u) ? __uint_as_float(u & 0x7fffffffu) : __uint_as_float(~u);
}
__device__ __forceinline__ float lrelu(float x) { return fmaxf(x, 0.2f * x); }

// ---------------- init: global_feats = mono(-1e9) ----------------
__global__ void sc_init(unsigned* __restrict__ gf, int total4) {
  int i = blockIdx.x * blockDim.x + threadIdx.x;
  if (i < total4) {
    unsigned m = f2mono(-1.0e9f);
    ((uint4*)gf)[i] = make_uint4(m, m, m, m);
  }
}

// ---------------- fused: gather + layer1(fp32) + layer2(split-bf16 MFMA) + seg-amax ----------------
// 128 points per block-iteration; 4 waves, wave w owns points [w*32, w*32+32) x all 128 features.
__global__ __launch_bounds__(256, 2) void sc_main(
    const float* __restrict__ muons, const int* __restrict__ bidx,
    const float* __restrict__ cond, const float* __restrict__ W1,
    const float* __restrict__ b1, const float* __restrict__ W2,
    const float* __restrict__ b2, unsigned* __restrict__ gf, int N) {
  __shared__ __align__(16) float w1s[448];
  __shared__ __align__(16) float b1s[64];
  __shared__ __align__(16) float b2s[128];
  __shared__ __align__(16) __bf16 w2t_hi[8192];  // [j=128][k=64], rows XOR-swizzled
  __shared__ __align__(16) __bf16 w2t_lo[8192];
  __shared__ __align__(16) __bf16 h_hi[8192];    // [p=128][k=64], rows XOR-swizzled
  __shared__ __align__(16) __bf16 h_lo[8192];
  __shared__ int idx_s[128];
  __shared__ float red[512];

  const int t = threadIdx.x;
  const int w = t >> 6;
  const int lane = t & 63;
  const int col = lane & 31;
  const int kh2 = lane >> 5;

  // one-time weight staging
  for (int i = t; i < 448; i += 256) w1s[i] = W1[i];
  if (t < 64) b1s[t] = b1[t];
  if (t < 128) b2s[t] = b2[t];
  {
    const int j = t & 127;
    const int kh = t >> 7;
    const int swz = (j & 7) << 3;
    for (int kk = 0; kk < 32; ++kk) {
      const int k = kh * 32 + kk;
      const float v = W2[k * 128 + j];
      const __bf16 hb = (__bf16)v;
      const __bf16 lb = (__bf16)(v - (float)hb);
      const int sa = j * 64 + (k ^ swz);
      w2t_hi[sa] = hb;
      w2t_lo[sa] = lb;
    }
  }
  __syncthreads();

  const int niter = (N + 127) >> 7;
  for (int it = blockIdx.x; it < niter; it += gridDim.x) {
    const int pbase = it << 7;
    const int npts = min(128, N - pbase);

    // ---- stage 1: inputs + layer1 (2 threads/point, each does 32 of 64 h) ----
    {
      const int p = t & 127;
      const int hf = t >> 7;
      const int gp = pbase + p;
      const int bi = bidx[min(gp, N - 1)];
      if (hf == 0) idx_s[p] = bi;
      float in[7];
      #pragma unroll
      for (int k = 0; k < 7; ++k) in[k] = 0.0f;
      if (gp < N) {
        in[0] = muons[gp * 3 + 0];
        in[1] = muons[gp * 3 + 1];
        in[2] = muons[gp * 3 + 2];
        const f32x4 c4 = *(const f32x4*)&cond[bi * 4];
        in[3] = c4.x; in[4] = c4.y; in[5] = c4.z; in[6] = c4.w;
      }
      const int j0 = hf * 32;
      const int swz = (p & 7) << 3;
      #pragma unroll
      for (int c = 0; c < 4; ++c) {
        f32x4 a0 = *(const f32x4*)&b1s[j0 + c * 8];
        f32x4 a1 = *(const f32x4*)&b1s[j0 + c * 8 + 4];
        #pragma unroll
        for (int k = 0; k < 7; ++k) {
          a0 += in[k] * (*(const f32x4*)&w1s[k * 64 + j0 + c * 8]);
          a1 += in[k] * (*(const f32x4*)&w1s[k * 64 + j0 + c * 8 + 4]);
        }
        bf16x8 hi8, lo8;
        #pragma unroll
        for (int e = 0; e < 8; ++e) {
          float x = (e < 4) ? a0[e] : a1[e - 4];
          x = lrelu(x);
          const __bf16 hb = (__bf16)x;
          hi8[e] = hb;
          lo8[e] = (__bf16)(x - (float)hb);
        }
        const int sa = p * 64 + ((j0 + c * 8) ^ swz);
        *(bf16x8*)&h_hi[sa] = hi8;
        *(bf16x8*)&h_lo[sa] = lo8;
      }
    }
    __syncthreads();

    // ---- stage 2: layer2 via split-bf16 MFMA (3 products ~= fp32) ----
    f32x16 acc[4];
    #pragma unroll
    for (int jt = 0; jt < 4; ++jt)
      #pragma unroll
      for (int e = 0; e < 16; ++e) acc[jt][e] = 0.0f;
    {
      const int pl = (w << 5) + col;
      const int abase = pl * 64;
      const int aswz = (pl & 7) << 3;
      #pragma unroll
      for (int ks = 0; ks < 4; ++ks) {
        const int kst = ks * 16 + kh2 * 8;
        const bf16x8 Ah = *(const bf16x8*)&h_hi[abase + (kst ^ aswz)];
        const bf16x8 Al = *(const bf16x8*)&h_lo[abase + (kst ^ aswz)];
        #pragma unroll
        for (int jt = 0; jt < 4; ++jt) {
          const int j = jt * 32 + col;
          const int bsa = j * 64 + (kst ^ ((j & 7) << 3));
          const bf16x8 Bh = *(const bf16x8*)&w2t_hi[bsa];
          const bf16x8 Bl = *(const bf16x8*)&w2t_lo[bsa];
          acc[jt] = __builtin_amdgcn_mfma_f32_32x32x16_bf16(Ah, Bh, acc[jt], 0, 0, 0);
          acc[jt] = __builtin_amdgcn_mfma_f32_32x32x16_bf16(Ah, Bl, acc[jt], 0, 0, 0);
          acc[jt] = __builtin_amdgcn_mfma_f32_32x32x16_bf16(Al, Bh, acc[jt], 0, 0, 0);
        }
      }
    }

    // ---- epilogue: bias + lrelu ----
    #pragma unroll
    for (int jt = 0; jt < 4; ++jt) {
      const float bb = b2s[jt * 32 + col];
      #pragma unroll
      for (int r = 0; r < 16; ++r) acc[jt][r] = lrelu(acc[jt][r] + bb);
    }

    // ---- segmented max: D row r of reg = (r&3)+8*(r>>2)+4*kh2 ----
    int pbi[16];
    bool pv[16];
    #pragma unroll
    for (int r = 0; r < 16; ++r) {
      const int rr = (r & 3) + ((r >> 2) << 3) + (kh2 << 2);
      const int pl = (w << 5) + rr;
      pbi[r] = idx_s[pl];
      pv[r] = (pbase + pl) < N;
    }
    const int bA = idx_s[0];
    const int bB = idx_s[npts - 1];
    for (int b = bA; b <= bB; ++b) {
      #pragma unroll
      for (int jt = 0; jt < 4; ++jt) {
        float m = -3.0e38f;
        #pragma unroll
        for (int r = 0; r < 16; ++r)
          if (pv[r] && (pbi[r] == b)) m = fmaxf(m, acc[jt][r]);
        m = fmaxf(m, __shfl_xor(m, 32));
        if (lane < 32) red[w * 128 + jt * 32 + col] = m;
      }
      __syncthreads();
      if (t < 128) {
        const float mm = fmaxf(fmaxf(red[t], red[128 + t]),
                               fmaxf(red[256 + t], red[384 + t]));
        if (mm > -2.9e38f) atomicMax(&gf[b * 128 + t], f2mono(mm));
      }
      __syncthreads();
    }
  }
}

// ---------------- decision MLP: [B,132] @ W3 -> lrelu -> @ W4 + b4 ----------------
__global__ __launch_bounds__(128) void sc_final(
    const unsigned* __restrict__ gf, const float* __restrict__ cond,
    const float* __restrict__ W3, const float* __restrict__ b3,
    const float* __restrict__ W4, const float* __restrict__ b4,
    float* __restrict__ out, int B) {
  __shared__ __align__(16) float w3t[128 * 132];  // [j][k]
  __shared__ float b3s[128], w4s[128];
  __shared__ __align__(16) float din[8 * 132];
  __shared__ float wred[16];
  const int t = threadIdx.x;
  for (int k = 0; k < 132; ++k) w3t[t * 132 + k] = W3[k * 128 + t];
  b3s[t] = b3[t];
  w4s[t] = W4[t];
  __syncthreads();

  const int nocts = (B + 7) >> 3;
  for (int oc = blockIdx.x; oc < nocts; oc += gridDim.x) {
    const int rbase = oc << 3;
    #pragma unroll
    for (int r = 0; r < 8; ++r) {
      const int row = rbase + r;
      if (row < B) {
        din[r * 132 + t] = mono2f(gf[row * 128 + t]);
        if (t < 4) din[r * 132 + 128 + t] = cond[row * 4 + t];
      }
    }
    __syncthreads();
    float a8[8];
    #pragma unroll
    for (int r = 0; r < 8; ++r) a8[r] = b3s[t];
    for (int kg = 0; kg < 33; ++kg) {
      const f32x4 wv = *(const f32x4*)&w3t[t * 132 + kg * 4];
      #pragma unroll
      for (int r = 0; r < 8; ++r) {
        const f32x4 dv = *(const f32x4*)&din[r * 132 + kg * 4];
        a8[r] += wv[0] * dv[0] + wv[1] * dv[1] + wv[2] * dv[2] + wv[3] * dv[3];
      }
    }
    const float w4v = w4s[t];
    #pragma unroll
    for (int r = 0; r < 8; ++r) a8[r] = lrelu(a8[r]) * w4v;
    const int lane = t & 63;
    const int wv_ = t >> 6;
    #pragma unroll
    for (int r = 0; r < 8; ++r) {
      float s = a8[r];
      s += __shfl_xor(s, 1);  s += __shfl_xor(s, 2);
      s += __shfl_xor(s, 4);  s += __shfl_xor(s, 8);
      s += __shfl_xor(s, 16); s += __shfl_xor(s, 32);
      if (lane == 0) wred[wv_ * 8 + r] = s;
    }
    __syncthreads();
    if (t < 8) {
      const int row = rbase + t;
      if (row < B) out[row] = wred[t] + wred[8 + t] + b4[0];
    }
    __syncthreads();
  }
}

extern "C" void kernel_launch(void* const* d_in, const int* in_sizes, int n_in,
                              void* d_out, int out_size, void* d_ws, size_t ws_size,
                              hipStream_t stream) {
  const float* muons = (const float*)d_in[0];
  const int* bidx = (const int*)d_in[1];
  const float* cond = (const float*)d_in[2];
  // d_in[3] = batch_size scalar (device); B derived host-side from out_size instead
  const float* W1 = (const float*)d_in[4];
  const float* b1 = (const float*)d_in[5];
  const float* W2 = (const float*)d_in[6];
  const float* b2 = (const float*)d_in[7];
  const float* W3 = (const float*)d_in[8];
  const float* b3 = (const float*)d_in[9];
  const float* W4 = (const float*)d_in[10];
  const float* b4 = (const float*)d_in[11];
  float* out = (float*)d_out;
  const int N = in_sizes[1];   // batch_index has N elements
  const int B = out_size;      // score is [B,1]
  unsigned* gf = (unsigned*)d_ws;  // B*128 mono-encoded uints (8 MB)

  const int total4 = (B * 128) / 4;
  sc_init<<<(total4 + 255) / 256, 256, 0, stream>>>(gf, total4);
  sc_main<<<1024, 256, 0, stream>>>(muons, bidx, cond, W1, b1, W2, b2, gf, N);
  sc_final<<<1024, 128, 0, stream>>>(gf, cond, W3, b3, W4, b4, out, B);
  (void)n_in; (void)ws_size;
}